// Round 1
// 878.789 us; speedup vs baseline: 1.0287x; 1.0287x over previous
//
#include <hip/hip_runtime.h>
#include <hip/hip_bf16.h>
#include <math.h>

#define DD 512
#define EPSF 1e-8f
#define BM 128
#define BN 128
#define BK 32
#define FBIG 3.402823466e+38f
#define NPART 2048

typedef __bf16 bf16_t;
typedef __bf16 bf16x4_t __attribute__((ext_vector_type(4)));
typedef __bf16 bf16x8_t __attribute__((ext_vector_type(8)));
typedef float f32x4 __attribute__((ext_vector_type(4)));

// ---------------- W fp32 -> bf16 (native [j][k] layout) ----------------
__global__ void k_convW(const float* __restrict__ W, bf16_t* __restrict__ Wb) {
    int i = blockIdx.x * blockDim.x + threadIdx.x;
    float4 v = ((const float4*)W)[i];
    bf16x4_t o;
    o[0] = (bf16_t)v.x; o[1] = (bf16_t)v.y; o[2] = (bf16_t)v.z; o[3] = (bf16_t)v.w;
    ((bf16x4_t*)Wb)[i] = o;
}

// ---------------- partial column sums + optional z->bf16 conversion ----------------
template<bool CONV>
__global__ void k_colsum(const float* __restrict__ z, bf16_t* __restrict__ zb,
                         float* __restrict__ part, int N, int rpb) {
    int t = threadIdx.x;                 // 256
    int b = blockIdx.x;                  // NPART
    int col4 = t & 127, sub = t >> 7;
    int r0 = b * rpb, r1 = min(r0 + rpb, N);
    const float4* z4 = (const float4*)z;
    float4 acc = make_float4(0.f, 0.f, 0.f, 0.f);
    #pragma unroll 4
    for (int r = r0 + sub; r < r1; r += 2) {
        float4 v = z4[(size_t)r * 128 + col4];
        if (CONV) {
            bf16x4_t o;
            o[0] = (bf16_t)v.x; o[1] = (bf16_t)v.y; o[2] = (bf16_t)v.z; o[3] = (bf16_t)v.w;
            ((bf16x4_t*)zb)[(size_t)r * 128 + col4] = o;
        }
        acc.x += v.x; acc.y += v.y; acc.z += v.z; acc.w += v.w;
    }
    __shared__ float4 sm[128];
    if (sub == 1) sm[col4] = acc;
    __syncthreads();
    if (sub == 0) {
        float4 o = sm[col4];
        acc.x += o.x; acc.y += o.y; acc.z += o.z; acc.w += o.w;
        ((float4*)(part + (size_t)b * DD))[col4] = acc;
    }
}

// reduce NPART partial vectors -> one [512] vector; one block per column
__global__ void k_reduceP(const float* __restrict__ part, float* __restrict__ outv, float scale) {
    __shared__ float sm[256];
    int j = blockIdx.x;
    int t = threadIdx.x;
    float s = 0.f;
    #pragma unroll
    for (int p = 0; p < NPART / 256; ++p) s += part[(size_t)(p * 256 + t) * DD + j];
    sm[t] = s;
    __syncthreads();
    for (int st = 128; st > 0; st >>= 1) {
        if (t < st) sm[t] += sm[t + st];
        __syncthreads();
    }
    if (t == 0) outv[j] = sm[0] * scale;
}

// ---------------- FUSED: d2 + online softmax + weighted vector accumulation ----------------
// Each 16-lane group owns one row per iteration: computes d2 (fp32-exact),
// maintains running min m, running sumexp s, and a 32-float-per-lane weighted
// z accumulator (rescaled only on new minima - rare). Eliminates the separate
// 205 MB zb re-read pass; c is now accumulated from fp32 z (better numerics).
__global__ __launch_bounds__(256, 4) void k_d2w(
    const float* __restrict__ z, const float* __restrict__ cbar,
    float* __restrict__ part, float* __restrict__ mpart,
    float* __restrict__ spart, int N)
{
    __shared__ float4 cs[128];          // cbar in LDS (broadcast reads, frees 32 VGPR)
    __shared__ float4 vsm[4][128];      // per-wave vector partials
    __shared__ float wm[4], wsv[4];
    int t = threadIdx.x;
    int lane = t & 63, wv = t >> 6;
    int l15 = lane & 15, r4 = lane >> 4;
    if (t < 128) cs[t] = ((const float4*)cbar)[t];
    __syncthreads();

    int gw = (blockIdx.x * 256 + t) >> 6;
    int nw = (gridDim.x * 256) >> 6;
    float m = FBIG, s = 0.f;
    float4 acc[8];
    #pragma unroll
    for (int q = 0; q < 8; ++q) acc[q] = make_float4(0.f, 0.f, 0.f, 0.f);

    for (int r = gw * 4 + r4; r < N; r += nw * 4) {
        const float4* zr = (const float4*)(z + (size_t)r * DD);
        float4 vv[8];
        float sum = 0.f;
        #pragma unroll
        for (int q = 0; q < 8; ++q) {
            float4 v = zr[q * 16 + l15];
            float4 c = cs[q * 16 + l15];
            vv[q] = v;
            float d;
            d = v.x - c.x; sum += d * d;
            d = v.y - c.y; sum += d * d;
            d = v.z - c.z; sum += d * d;
            d = v.w - c.w; sum += d * d;
        }
        #pragma unroll
        for (int off = 1; off < 16; off <<= 1) sum += __shfl_xor(sum, off, 64);
        float w;
        if (sum < m) {                  // new min: rescale (group-uniform, rare)
            float f = __expf(-2.0f * (m - sum));   // m==FBIG -> f==0, acc stays 0
            s *= f;
            #pragma unroll
            for (int q = 0; q < 8; ++q) {
                acc[q].x *= f; acc[q].y *= f; acc[q].z *= f; acc[q].w *= f;
            }
            m = sum;
            w = 1.0f;
        } else {
            w = __expf(-2.0f * (sum - m));
        }
        s += w;
        #pragma unroll
        for (int q = 0; q < 8; ++q) {
            acc[q].x += w * vv[q].x; acc[q].y += w * vv[q].y;
            acc[q].z += w * vv[q].z; acc[q].w += w * vv[q].w;
        }
    }

    // combine the 4 row-groups within the wave (scale to wave min first)
    float mw = fminf(m, __shfl_xor(m, 16, 64));
    mw = fminf(mw, __shfl_xor(mw, 32, 64));
    float f = __expf(-2.0f * (m - mw));
    s *= f;
    #pragma unroll
    for (int q = 0; q < 8; ++q) {
        acc[q].x *= f; acc[q].y *= f; acc[q].z *= f; acc[q].w *= f;
    }
    #pragma unroll
    for (int off = 16; off < 64; off <<= 1) {
        s += __shfl_xor(s, off, 64);
        #pragma unroll
        for (int q = 0; q < 8; ++q) {
            acc[q].x += __shfl_xor(acc[q].x, off, 64);
            acc[q].y += __shfl_xor(acc[q].y, off, 64);
            acc[q].z += __shfl_xor(acc[q].z, off, 64);
            acc[q].w += __shfl_xor(acc[q].w, off, 64);
        }
    }
    if (lane < 16) {
        #pragma unroll
        for (int q = 0; q < 8; ++q) vsm[wv][q * 16 + l15] = acc[q];
        if (lane == 0) { wm[wv] = mw; wsv[wv] = s; }
    }
    __syncthreads();
    if (t < 128) {
        float M = fminf(fminf(wm[0], wm[1]), fminf(wm[2], wm[3]));
        float4 o = make_float4(0.f, 0.f, 0.f, 0.f);
        #pragma unroll
        for (int w2 = 0; w2 < 4; ++w2) {
            float fw = __expf(-2.0f * (wm[w2] - M));
            float4 a = vsm[w2][t];
            o.x += fw * a.x; o.y += fw * a.y; o.z += fw * a.z; o.w += fw * a.w;
        }
        ((float4*)(part + (size_t)blockIdx.x * DD))[t] = o;
        if (t == 0) {
            float S = 0.f;
            #pragma unroll
            for (int w2 = 0; w2 < 4; ++w2) S += wsv[w2] * __expf(-2.0f * (wm[w2] - M));
            mpart[blockIdx.x] = M;
            spart[blockIdx.x] = S;
        }
    }
}

// combine NPART (m,s) partials -> per-partial weight scale e^{-2(m_b-M)}/S
__global__ void k_combine2(const float* __restrict__ mpart, const float* __restrict__ spart,
                           float* __restrict__ wscale) {
    __shared__ float smm[256], sms[256];
    int t = threadIdx.x;
    float M = FBIG;
    for (int i = t; i < NPART; i += 256) M = fminf(M, mpart[i]);
    smm[t] = M;
    __syncthreads();
    for (int st = 128; st > 0; st >>= 1) {
        if (t < st) smm[t] = fminf(smm[t], smm[t + st]);
        __syncthreads();
    }
    M = smm[0];
    float S = 0.f;
    for (int i = t; i < NPART; i += 256) S += spart[i] * __expf(-2.0f * (mpart[i] - M));
    sms[t] = S;
    __syncthreads();
    for (int st = 128; st > 0; st >>= 1) {
        if (t < st) sms[t] += sms[t + st];
        __syncthreads();
    }
    float inv = 1.0f / sms[0];
    for (int i = t; i < NPART; i += 256) wscale[i] = __expf(-2.0f * (mpart[i] - M)) * inv;
}

// reduce NPART weighted partial vectors -> cvec
__global__ void k_reducePW(const float* __restrict__ part, const float* __restrict__ wscale,
                           float* __restrict__ outv) {
    __shared__ float sm[256];
    int j = blockIdx.x, t = threadIdx.x;
    float s = 0.f;
    #pragma unroll
    for (int p = 0; p < NPART / 256; ++p) {
        int b = p * 256 + t;
        s += part[(size_t)b * DD + j] * wscale[b];
    }
    sm[t] = s;
    __syncthreads();
    for (int st = 128; st > 0; st >>= 1) {
        if (t < st) sm[t] += sm[t + st];
        __syncthreads();
    }
    if (t == 0) outv[j] = sm[0];
}

// ---------------- cnorm_inv ----------------
__global__ void k_cnorm(const float* __restrict__ cvec, float* __restrict__ outp) {
    __shared__ float sm[512];
    float v = cvec[threadIdx.x];
    sm[threadIdx.x] = v * v;
    __syncthreads();
    for (int st = 256; st > 0; st >>= 1) {
        if (threadIdx.x < st) sm[threadIdx.x] += sm[threadIdx.x + st];
        __syncthreads();
    }
    if (threadIdx.x == 0) outp[0] = 1.0f / fmaxf(sqrtf(sm[0]), EPSF);
}

// ---------------- MFMA GEMM: 256 thr, 128x128 tile, split-4 cols ----------------
// ZB=true: A staged from bf16 zb via global_load_lds (no VALU in K-loop).
// ZB=false: fallback, A prefetched fp32 + converted (round-4 path).
template<bool ZB>
__global__ __launch_bounds__(256, 4) void k_gemm(
    const float* __restrict__ z, const bf16_t* __restrict__ zb,
    const bf16_t* __restrict__ Wb, const float* __restrict__ bvec,
    const float* __restrict__ cvec, float* __restrict__ sqp, float* __restrict__ dtp,
    int N, int npad)
{
    __shared__ bf16_t As[BM * BK];      // 8 KB [m][k]
    __shared__ bf16_t Bs[BN * BK];      // 8 KB [n][k]
    __shared__ float psq[BM][8];
    __shared__ float pdt[BM][8];

    const int t    = threadIdx.x;
    const int lane = t & 63;
    const int wv   = t >> 6;            // 0..3
    const int wr   = wv >> 1;
    const int wc   = wv & 1;
    const int quad = lane >> 4;
    const int l15  = lane & 15;
    const int cb   = blockIdx.x;        // col-block 0..3
    const int row0 = blockIdx.y * BM;

    // B DMA: round q: col = cb*128 + q*64 + (t>>2), 16 B at elem-off (t&3)*8
    const bf16_t* bp = Wb + (size_t)(cb * BN + (t >> 2)) * DD + (t & 3) * 8;
    // A DMA (ZB): row = row0 + q*64 + (t>>2)  (npad-padded, always in-bounds)
    const bf16_t* ap = zb + (size_t)(row0 + (t >> 2)) * DD + (t & 3) * 8;

    // A fallback (fp32): thread t -> row t>>1, k-half (t&1)*16 floats
    const int arow = t >> 1;
    const int ah   = t & 1;
    int rowe = row0 + arow; if (rowe >= N) rowe = N - 1;
    const float4* zp4 = (const float4*)(z + (size_t)rowe * DD + ah * 16);

    f32x4 acc[4][4];
    #pragma unroll
    for (int a = 0; a < 4; ++a)
        #pragma unroll
        for (int b = 0; b < 4; ++b) acc[a][b] = (f32x4){0.f, 0.f, 0.f, 0.f};

    float4 v0, v1, v2, v3;
    if (!ZB) { v0 = zp4[0]; v1 = zp4[1]; v2 = zp4[2]; v3 = zp4[3]; }

    for (int kc = 0; kc < DD; kc += BK) {
        if (kc) __syncthreads();        // #1: previous compute done, LDS reusable

        #pragma unroll
        for (int q = 0; q < 2; ++q) {   // B: 2 DMA rounds of 256 x 16 B
            int ldsoff = __builtin_amdgcn_readfirstlane(q * 4096 + wv * 1024);
            __builtin_amdgcn_global_load_lds(
                (const __attribute__((address_space(1))) unsigned int*)(const void*)(bp + (size_t)q * 64 * DD + kc),
                (__attribute__((address_space(3))) unsigned int*)(void*)((char*)Bs + ldsoff),
                16, 0, 0);
        }
        if (ZB) {
            #pragma unroll
            for (int q = 0; q < 2; ++q) {   // A: 2 DMA rounds of 256 x 16 B
                int ldsoff = __builtin_amdgcn_readfirstlane(q * 4096 + wv * 1024);
                __builtin_amdgcn_global_load_lds(
                    (const __attribute__((address_space(1))) unsigned int*)(const void*)(ap + (size_t)q * 64 * DD + kc),
                    (__attribute__((address_space(3))) unsigned int*)(void*)((char*)As + ldsoff),
                    16, 0, 0);
            }
        } else {
            bf16x8_t lo, hi;
            lo[0]=(bf16_t)v0.x; lo[1]=(bf16_t)v0.y; lo[2]=(bf16_t)v0.z; lo[3]=(bf16_t)v0.w;
            lo[4]=(bf16_t)v1.x; lo[5]=(bf16_t)v1.y; lo[6]=(bf16_t)v1.z; lo[7]=(bf16_t)v1.w;
            hi[0]=(bf16_t)v2.x; hi[1]=(bf16_t)v2.y; hi[2]=(bf16_t)v2.z; hi[3]=(bf16_t)v2.w;
            hi[4]=(bf16_t)v3.x; hi[5]=(bf16_t)v3.y; hi[6]=(bf16_t)v3.z; hi[7]=(bf16_t)v3.w;
            *(bf16x8_t*)(As + arow * BK + ah * 16)     = lo;
            *(bf16x8_t*)(As + arow * BK + ah * 16 + 8) = hi;
        }

        __syncthreads();                // #2: drains DMA (vmcnt) + LDS writes

        if (!ZB && kc + BK < DD) {
            int kf = (kc + BK) >> 2;
            v0 = zp4[kf]; v1 = zp4[kf + 1]; v2 = zp4[kf + 2]; v3 = zp4[kf + 3];
        }

        bf16x8_t af[4];
        #pragma unroll
        for (int rt = 0; rt < 4; ++rt)
            af[rt] = *(const bf16x8_t*)(As + (wr * 64 + rt * 16 + l15) * BK + quad * 8);
        #pragma unroll
        for (int ct = 0; ct < 4; ++ct) {
            bf16x8_t bfv = *(const bf16x8_t*)(Bs + (wc * 64 + ct * 16 + l15) * BK + quad * 8);
            #pragma unroll
            for (int rt = 0; rt < 4; ++rt)
                acc[rt][ct] = __builtin_amdgcn_mfma_f32_16x16x32_bf16(af[rt], bfv, acc[rt][ct], 0, 0, 0);
        }
    }

    // epilogue: x = acc + b[col]; per-row partial sq and dot(c) over this col-block.
    // 2-step shfl only (4-lane partial), LDS combine sums 8 slots.
    float bc[4], cc[4];
    #pragma unroll
    for (int ct = 0; ct < 4; ++ct) {
        int col = cb * BN + wc * 64 + ct * 16 + l15;
        bc[ct] = bvec[col];
        cc[ct] = cvec[col];
    }
    #pragma unroll
    for (int rt = 0; rt < 4; ++rt) {
        #pragma unroll
        for (int rg = 0; rg < 4; ++rg) {
            float sq = 0.f, dt = 0.f;
            #pragma unroll
            for (int ct = 0; ct < 4; ++ct) {
                float x = acc[rt][ct][rg] + bc[ct];
                sq += x * x;
                dt += x * cc[ct];
            }
            sq += __shfl_xor(sq, 1, 64); dt += __shfl_xor(dt, 1, 64);
            sq += __shfl_xor(sq, 2, 64); dt += __shfl_xor(dt, 2, 64);
            if ((l15 & 3) == 0) {
                int rl = wr * 64 + rt * 16 + quad * 4 + rg;
                psq[rl][wc * 4 + (l15 >> 2)] = sq;
                pdt[rl][wc * 4 + (l15 >> 2)] = dt;
            }
        }
    }
    __syncthreads();
    if (t < BM) {
        int r = row0 + t;
        if (r < N) {
            float sq = 0.f, dt = 0.f;
            #pragma unroll
            for (int i = 0; i < 8; ++i) { sq += psq[t][i]; dt += pdt[t][i]; }
            sqp[(size_t)cb * npad + r] = sq;
            dtp[(size_t)cb * npad + r] = dt;
        }
    }
}

// ---------------- combine 4 col-block partials -> dist ----------------
__global__ void k_final(const float* __restrict__ sqp, const float* __restrict__ dtp,
                        const float* __restrict__ cninv, float* __restrict__ out,
                        int N, int npad) {
    int r = blockIdx.x * blockDim.x + threadIdx.x;
    if (r < N) {
        float sq = sqp[r] + sqp[(size_t)npad + r] + sqp[2 * (size_t)npad + r] + sqp[3 * (size_t)npad + r];
        float dt = dtp[r] + dtp[(size_t)npad + r] + dtp[2 * (size_t)npad + r] + dtp[3 * (size_t)npad + r];
        out[r] = 1.0f - dt * cninv[0] / fmaxf(sqrtf(sq), EPSF);
    }
}

extern "C" void kernel_launch(void* const* d_in, const int* in_sizes, int n_in,
                              void* d_out, int out_size, void* d_ws, size_t ws_size,
                              hipStream_t stream)
{
    const float* z = (const float*)d_in[0];
    const float* W = (const float*)d_in[1];
    const float* b = (const float*)d_in[2];
    float* out = (float*)d_out;
    int N = in_sizes[0] / DD;
    int npad = ((N + BM - 1) / BM) * BM;

    float* ws = (float*)d_ws;
    size_t off = 0;
    float* part   = ws + off; off += (size_t)NPART * DD;
    float* cbar   = ws + off; off += DD;
    float* mpart  = ws + off; off += NPART;
    float* spart  = ws + off; off += NPART;
    float* wscale = ws + off; off += NPART;
    float* cvec   = ws + off; off += DD;
    float* cninv  = ws + off; off += 1;
    off = (off + 3) & ~(size_t)3;
    float* sqp    = ws + off; off += (size_t)4 * npad;
    float* dtp    = ws + off; off += (size_t)4 * npad;
    bf16_t* Wb    = (bf16_t*)(ws + off); off += (size_t)DD * DD / 2;
    bf16_t* zb    = (bf16_t*)(ws + off);
    size_t need_bytes = (off + (size_t)npad * DD / 2) * sizeof(float);
    const bool use_zb = ws_size >= need_bytes;

    int rpb = (N + NPART - 1) / NPART;

    k_convW<<<256, 256, 0, stream>>>(W, Wb);
    if (use_zb) k_colsum<true ><<<NPART, 256, 0, stream>>>(z, zb, part, N, rpb);
    else        k_colsum<false><<<NPART, 256, 0, stream>>>(z, zb, part, N, rpb);
    k_reduceP<<<DD, 256, 0, stream>>>(part, cbar, 1.0f / (float)N);
    k_d2w<<<NPART, 256, 0, stream>>>(z, cbar, part, mpart, spart, N);
    k_combine2<<<1, 256, 0, stream>>>(mpart, spart, wscale);
    k_reducePW<<<DD, 256, 0, stream>>>(part, wscale, cvec);
    k_cnorm<<<1, DD, 0, stream>>>(cvec, cninv);
    dim3 grid(4, npad / BM);
    if (use_zb) k_gemm<true ><<<grid, 256, 0, stream>>>(z, zb, Wb, b, cvec, sqp, dtp, N, npad);
    else        k_gemm<false><<<grid, 256, 0, stream>>>(z, zb, Wb, b, cvec, sqp, dtp, N, npad);
    k_final<<<(N + 255) / 256, 256, 0, stream>>>(sqp, dtp, cninv, out, N, npad);
}

// Round 2
// 857.457 us; speedup vs baseline: 1.0543x; 1.0249x over previous
//
#include <hip/hip_runtime.h>
#include <hip/hip_bf16.h>
#include <math.h>

#define DD 512
#define EPSF 1e-8f
#define BM 128
#define BN 128
#define BK 32
#define FBIG 3.402823466e+38f
#define NPART 2048

typedef __bf16 bf16_t;
typedef __bf16 bf16x4_t __attribute__((ext_vector_type(4)));
typedef __bf16 bf16x8_t __attribute__((ext_vector_type(8)));
typedef float f32x4 __attribute__((ext_vector_type(4)));

__device__ inline float bf2f(unsigned short u) {
    return __uint_as_float(((unsigned int)u) << 16);
}

// ---------------- W fp32 -> bf16 (native [j][k] layout) ----------------
__global__ void k_convW(const float* __restrict__ W, bf16_t* __restrict__ Wb) {
    int i = blockIdx.x * blockDim.x + threadIdx.x;
    float4 v = ((const float4*)W)[i];
    bf16x4_t o;
    o[0] = (bf16_t)v.x; o[1] = (bf16_t)v.y; o[2] = (bf16_t)v.z; o[3] = (bf16_t)v.w;
    ((bf16x4_t*)Wb)[i] = o;
}

// ---------------- partial column sums + optional z->bf16 conversion ----------------
template<bool CONV>
__global__ void k_colsum(const float* __restrict__ z, bf16_t* __restrict__ zb,
                         float* __restrict__ part, int N, int rpb) {
    int t = threadIdx.x;                 // 256
    int b = blockIdx.x;                  // NPART
    int col4 = t & 127, sub = t >> 7;
    int r0 = b * rpb, r1 = min(r0 + rpb, N);
    const float4* z4 = (const float4*)z;
    float4 acc = make_float4(0.f, 0.f, 0.f, 0.f);
    #pragma unroll 4
    for (int r = r0 + sub; r < r1; r += 2) {
        float4 v = z4[(size_t)r * 128 + col4];
        if (CONV) {
            bf16x4_t o;
            o[0] = (bf16_t)v.x; o[1] = (bf16_t)v.y; o[2] = (bf16_t)v.z; o[3] = (bf16_t)v.w;
            ((bf16x4_t*)zb)[(size_t)r * 128 + col4] = o;
        }
        acc.x += v.x; acc.y += v.y; acc.z += v.z; acc.w += v.w;
    }
    __shared__ float4 sm[128];
    if (sub == 1) sm[col4] = acc;
    __syncthreads();
    if (sub == 0) {
        float4 o = sm[col4];
        acc.x += o.x; acc.y += o.y; acc.z += o.z; acc.w += o.w;
        ((float4*)(part + (size_t)b * DD))[col4] = acc;
    }
}

// reduce NPART partial vectors -> one [512] vector; one block per column
__global__ void k_reduceP(const float* __restrict__ part, float* __restrict__ outv, float scale) {
    __shared__ float sm[256];
    int j = blockIdx.x;
    int t = threadIdx.x;
    float s = 0.f;
    #pragma unroll
    for (int p = 0; p < NPART / 256; ++p) s += part[(size_t)(p * 256 + t) * DD + j];
    sm[t] = s;
    __syncthreads();
    for (int st = 128; st > 0; st >>= 1) {
        if (t < st) sm[t] += sm[t + st];
        __syncthreads();
    }
    if (t == 0) outv[j] = sm[0] * scale;
}

// ---------------- FUSED: d2 + online softmax + weighted vector accumulation ----------------
__global__ __launch_bounds__(256, 4) void k_d2w(
    const float* __restrict__ z, const float* __restrict__ cbar,
    float* __restrict__ part, float* __restrict__ mpart,
    float* __restrict__ spart, int N)
{
    __shared__ float4 cs[128];
    __shared__ float4 vsm[4][128];
    __shared__ float wm[4], wsv[4];
    int t = threadIdx.x;
    int lane = t & 63, wv = t >> 6;
    int l15 = lane & 15, r4 = lane >> 4;
    if (t < 128) cs[t] = ((const float4*)cbar)[t];
    __syncthreads();

    int gw = (blockIdx.x * 256 + t) >> 6;
    int nw = (gridDim.x * 256) >> 6;
    float m = FBIG, s = 0.f;
    float4 acc[8];
    #pragma unroll
    for (int q = 0; q < 8; ++q) acc[q] = make_float4(0.f, 0.f, 0.f, 0.f);

    for (int r = gw * 4 + r4; r < N; r += nw * 4) {
        const float4* zr = (const float4*)(z + (size_t)r * DD);
        float4 vv[8];
        float sum = 0.f;
        #pragma unroll
        for (int q = 0; q < 8; ++q) {
            float4 v = zr[q * 16 + l15];
            float4 c = cs[q * 16 + l15];
            vv[q] = v;
            float d;
            d = v.x - c.x; sum += d * d;
            d = v.y - c.y; sum += d * d;
            d = v.z - c.z; sum += d * d;
            d = v.w - c.w; sum += d * d;
        }
        #pragma unroll
        for (int off = 1; off < 16; off <<= 1) sum += __shfl_xor(sum, off, 64);
        float w;
        if (sum < m) {
            float f = __expf(-2.0f * (m - sum));
            s *= f;
            #pragma unroll
            for (int q = 0; q < 8; ++q) {
                acc[q].x *= f; acc[q].y *= f; acc[q].z *= f; acc[q].w *= f;
            }
            m = sum;
            w = 1.0f;
        } else {
            w = __expf(-2.0f * (sum - m));
        }
        s += w;
        #pragma unroll
        for (int q = 0; q < 8; ++q) {
            acc[q].x += w * vv[q].x; acc[q].y += w * vv[q].y;
            acc[q].z += w * vv[q].z; acc[q].w += w * vv[q].w;
        }
    }

    float mw = fminf(m, __shfl_xor(m, 16, 64));
    mw = fminf(mw, __shfl_xor(mw, 32, 64));
    float f = __expf(-2.0f * (m - mw));
    s *= f;
    #pragma unroll
    for (int q = 0; q < 8; ++q) {
        acc[q].x *= f; acc[q].y *= f; acc[q].z *= f; acc[q].w *= f;
    }
    #pragma unroll
    for (int off = 16; off < 64; off <<= 1) {
        s += __shfl_xor(s, off, 64);
        #pragma unroll
        for (int q = 0; q < 8; ++q) {
            acc[q].x += __shfl_xor(acc[q].x, off, 64);
            acc[q].y += __shfl_xor(acc[q].y, off, 64);
            acc[q].z += __shfl_xor(acc[q].z, off, 64);
            acc[q].w += __shfl_xor(acc[q].w, off, 64);
        }
    }
    if (lane < 16) {
        #pragma unroll
        for (int q = 0; q < 8; ++q) vsm[wv][q * 16 + l15] = acc[q];
        if (lane == 0) { wm[wv] = mw; wsv[wv] = s; }
    }
    __syncthreads();
    if (t < 128) {
        float M = fminf(fminf(wm[0], wm[1]), fminf(wm[2], wm[3]));
        float4 o = make_float4(0.f, 0.f, 0.f, 0.f);
        #pragma unroll
        for (int w2 = 0; w2 < 4; ++w2) {
            float fw = __expf(-2.0f * (wm[w2] - M));
            float4 a = vsm[w2][t];
            o.x += fw * a.x; o.y += fw * a.y; o.z += fw * a.z; o.w += fw * a.w;
        }
        ((float4*)(part + (size_t)blockIdx.x * DD))[t] = o;
        if (t == 0) {
            float S = 0.f;
            #pragma unroll
            for (int w2 = 0; w2 < 4; ++w2) S += wsv[w2] * __expf(-2.0f * (wm[w2] - M));
            mpart[blockIdx.x] = M;
            spart[blockIdx.x] = S;
        }
    }
}

// combine NPART (m,s) partials -> per-partial weight scale e^{-2(m_b-M)}/S
__global__ void k_combine2(const float* __restrict__ mpart, const float* __restrict__ spart,
                           float* __restrict__ wscale) {
    __shared__ float smm[256], sms[256];
    int t = threadIdx.x;
    float M = FBIG;
    for (int i = t; i < NPART; i += 256) M = fminf(M, mpart[i]);
    smm[t] = M;
    __syncthreads();
    for (int st = 128; st > 0; st >>= 1) {
        if (t < st) smm[t] = fminf(smm[t], smm[t + st]);
        __syncthreads();
    }
    M = smm[0];
    float S = 0.f;
    for (int i = t; i < NPART; i += 256) S += spart[i] * __expf(-2.0f * (mpart[i] - M));
    sms[t] = S;
    __syncthreads();
    for (int st = 128; st > 0; st >>= 1) {
        if (t < st) sms[t] += sms[t + st];
        __syncthreads();
    }
    float inv = 1.0f / sms[0];
    for (int i = t; i < NPART; i += 256) wscale[i] = __expf(-2.0f * (mpart[i] - M)) * inv;
}

// reduce NPART weighted partial vectors -> cvec
__global__ void k_reducePW(const float* __restrict__ part, const float* __restrict__ wscale,
                           float* __restrict__ outv) {
    __shared__ float sm[256];
    int j = blockIdx.x, t = threadIdx.x;
    float s = 0.f;
    #pragma unroll
    for (int p = 0; p < NPART / 256; ++p) {
        int b = p * 256 + t;
        s += part[(size_t)b * DD + j] * wscale[b];
    }
    sm[t] = s;
    __syncthreads();
    for (int st = 128; st > 0; st >>= 1) {
        if (t < st) sm[t] += sm[t + st];
        __syncthreads();
    }
    if (t == 0) outv[j] = sm[0];
}

// ---------------- cnorm_inv ----------------
__global__ void k_cnorm(const float* __restrict__ cvec, float* __restrict__ outp) {
    __shared__ float sm[512];
    float v = cvec[threadIdx.x];
    sm[threadIdx.x] = v * v;
    __syncthreads();
    for (int st = 256; st > 0; st >>= 1) {
        if (threadIdx.x < st) sm[threadIdx.x] += sm[threadIdx.x + st];
        __syncthreads();
    }
    if (threadIdx.x == 0) outp[0] = 1.0f / fmaxf(sqrtf(sm[0]), EPSF);
}

// ======================= 256x256 / BK=64 / 8-wave counted-vmcnt GEMM =======================
// T2: XOR-swizzle (byte ^= (row&7)<<4) applied on the GLOBAL source (linear LDS dest,
//     same XOR on ds_read) -> ~2-way max bank conflict.
// T3/T4: double-buffered LDS, 2-deep prefetch, vmcnt(8) mid-loop (never 0).
// T5: setprio(1) around the 64-MFMA cluster.
// T1: bijective XCD swizzle; col-siblings of a row panel land adjacent on one XCD.
__global__ __launch_bounds__(512, 2) void k_gemm256(
    const bf16_t* __restrict__ zb, const bf16_t* __restrict__ Wb,
    const float* __restrict__ bvec, const float* __restrict__ cvec,
    float* __restrict__ sqp, float* __restrict__ dtp, int N, int npad)
{
    __shared__ bf16_t As[2 * 256 * 64];   // 64 KB, [buf][row][k]
    __shared__ bf16_t Bs[2 * 256 * 64];   // 64 KB, [buf][col][k]

    const int t    = threadIdx.x;         // 0..511
    const int lane = t & 63;
    const int wid  = t >> 6;              // 0..7
    const int wr   = wid >> 2;            // 0..1  (row half)
    const int wc   = wid & 3;             // 0..3  (col quarter)
    const int quad = lane >> 4;
    const int l15  = lane & 15;

    // XCD-aware bijective swizzle (m204)
    const int nwg = gridDim.x * gridDim.y;
    const int lid = blockIdx.y * gridDim.x + blockIdx.x;
    const int q8  = nwg >> 3, r8 = nwg & 7;
    const int xcd = lid & 7, idx = lid >> 3;
    const int wg  = (xcd < r8 ? xcd * (q8 + 1) : r8 * (q8 + 1) + (xcd - r8) * q8) + idx;
    const int cb     = wg & 1;            // col block (0..1)
    const int row0   = (wg >> 1) * 256;

    // staging source pointers: thread t covers (row = base + r*64 + (t>>3), 16 B at
    // byte ((t&7)*16) ^ ((row&7)<<4))  -- inverse swizzle on source, linear LDS dest
    const int tr = t >> 3;                // 0..63
    const int bo = ((t & 7) * 16) ^ ((tr & 7) << 4);
    const char* apt = (const char*)zb + (size_t)(row0 + tr) * (DD * 2) + bo;
    const char* bpt = (const char*)Wb + (size_t)(cb * 256 + tr) * (DD * 2) + bo;
    const int ldsw = __builtin_amdgcn_readfirstlane(wid * 1024);

#define STAGE256(buf, kt) do {                                                              \
    _Pragma("unroll")                                                                       \
    for (int r_ = 0; r_ < 4; ++r_) {                                                        \
        __builtin_amdgcn_global_load_lds(                                                   \
            (const __attribute__((address_space(1))) unsigned int*)(const void*)            \
                (apt + (size_t)r_ * 65536 + (kt) * 128),                                    \
            (__attribute__((address_space(3))) unsigned int*)(void*)                        \
                ((char*)As + (buf) * 32768 + r_ * 8192 + ldsw), 16, 0, 0);                  \
        __builtin_amdgcn_global_load_lds(                                                   \
            (const __attribute__((address_space(1))) unsigned int*)(const void*)            \
                (bpt + (size_t)r_ * 65536 + (kt) * 128),                                    \
            (__attribute__((address_space(3))) unsigned int*)(void*)                        \
                ((char*)Bs + (buf) * 32768 + r_ * 8192 + ldsw), 16, 0, 0);                  \
    }                                                                                       \
} while (0)

    // fragment read offsets (swizzled): row&7 == l15&7 for both A and B
    const int ka0 = (quad * 16) ^ ((l15 & 7) << 4);
    const int ka1 = ka0 ^ 64;
    const char* abase = (const char*)As + (wr * 128 + l15) * 128;
    const char* bbase = (const char*)Bs + (wc * 64 + l15) * 128;

    f32x4 acc[8][4];
    #pragma unroll
    for (int m = 0; m < 8; ++m)
        #pragma unroll
        for (int n = 0; n < 4; ++n) acc[m][n] = (f32x4){0.f, 0.f, 0.f, 0.f};

    // prologue: stage tiles 0 and 1; wait for tile 0 (own 8 oldest of 16)
    STAGE256(0, 0);
    STAGE256(1, 1);
    asm volatile("s_waitcnt vmcnt(8)" ::: "memory");
    __builtin_amdgcn_sched_barrier(0);
    __builtin_amdgcn_s_barrier();
    __builtin_amdgcn_sched_barrier(0);

    #pragma unroll
    for (int kt = 0; kt < 8; ++kt) {
        const int cur = kt & 1;
        bf16x8_t afr[8][2], bfr[4][2];
        #pragma unroll
        for (int m = 0; m < 8; ++m) {
            afr[m][0] = *(const bf16x8_t*)(abase + cur * 32768 + m * 2048 + ka0);
            afr[m][1] = *(const bf16x8_t*)(abase + cur * 32768 + m * 2048 + ka1);
        }
        #pragma unroll
        for (int n = 0; n < 4; ++n) {
            bfr[n][0] = *(const bf16x8_t*)(bbase + cur * 32768 + n * 2048 + ka0);
            bfr[n][1] = *(const bf16x8_t*)(bbase + cur * 32768 + n * 2048 + ka1);
        }
        asm volatile("s_waitcnt lgkmcnt(0)" ::: "memory");   // all my reads of buf[cur] done
        __builtin_amdgcn_sched_barrier(0);
        __builtin_amdgcn_s_barrier();                        // all waves done reading buf[cur]
        __builtin_amdgcn_sched_barrier(0);
        if (kt < 6) STAGE256(cur, kt + 2);                   // overwrite buf[cur] with tile kt+2
        __builtin_amdgcn_sched_barrier(0);
        __builtin_amdgcn_s_setprio(1);
        #pragma unroll
        for (int s = 0; s < 2; ++s)
            #pragma unroll
            for (int m = 0; m < 8; ++m)
                #pragma unroll
                for (int n = 0; n < 4; ++n)
                    acc[m][n] = __builtin_amdgcn_mfma_f32_16x16x32_bf16(
                        afr[m][s], bfr[n][s], acc[m][n], 0, 0, 0);
        __builtin_amdgcn_s_setprio(0);
        // retire next tile's 8 loads (kt+2's 8 stay in flight); drain at tail
        if (kt < 6) { asm volatile("s_waitcnt vmcnt(8)" ::: "memory"); }
        else        { asm volatile("s_waitcnt vmcnt(0)" ::: "memory"); }
        __builtin_amdgcn_sched_barrier(0);
        __builtin_amdgcn_s_barrier();                        // buf[cur^1] fully staged
        __builtin_amdgcn_sched_barrier(0);
    }
#undef STAGE256

    // ---- epilogue: x = acc + b[col]; per-row partial sq / dot(c) over this 256-col block ----
    // reuse As region as psq[256][16], pdt[256][16]
    float* psq = (float*)As;
    float* pdt = (float*)((char*)As + 16384);
    float bc[4], cc[4];
    #pragma unroll
    for (int n = 0; n < 4; ++n) {
        int col = cb * 256 + wc * 64 + n * 16 + l15;
        bc[n] = bvec[col];
        cc[n] = cvec[col];
    }
    #pragma unroll
    for (int m = 0; m < 8; ++m) {
        #pragma unroll
        for (int rg = 0; rg < 4; ++rg) {
            float sq = 0.f, dt = 0.f;
            #pragma unroll
            for (int n = 0; n < 4; ++n) {
                float x = acc[m][n][rg] + bc[n];
                sq += x * x;
                dt += x * cc[n];
            }
            sq += __shfl_xor(sq, 1, 64); dt += __shfl_xor(dt, 1, 64);
            sq += __shfl_xor(sq, 2, 64); dt += __shfl_xor(dt, 2, 64);
            if ((l15 & 3) == 0) {
                int row = wr * 128 + m * 16 + quad * 4 + rg;
                int slot = wc * 4 + (l15 >> 2);
                psq[row * 16 + slot] = sq;
                pdt[row * 16 + slot] = dt;
            }
        }
    }
    __syncthreads();
    if (t < 256) {
        int r = row0 + t;
        if (r < N) {
            const float4* p4 = (const float4*)(psq + t * 16);
            const float4* d4 = (const float4*)(pdt + t * 16);
            float sq = 0.f, dt = 0.f;
            #pragma unroll
            for (int i = 0; i < 4; ++i) {
                float4 a = p4[i], b2 = d4[i];
                sq += a.x + a.y + a.z + a.w;
                dt += b2.x + b2.y + b2.z + b2.w;
            }
            sqp[(size_t)cb * npad + r] = sq;
            dtp[(size_t)cb * npad + r] = dt;
        }
    }
}

// ---------------- fallback MFMA GEMM (fp32 A path, 128x128, proven) ----------------
__global__ __launch_bounds__(256, 4) void k_gemm_fb(
    const float* __restrict__ z, const bf16_t* __restrict__ Wb,
    const float* __restrict__ bvec, const float* __restrict__ cvec,
    float* __restrict__ sqp, float* __restrict__ dtp, int N, int npad)
{
    __shared__ bf16_t Asl[BM * BK];
    __shared__ bf16_t Bsl[BN * BK];
    __shared__ float psq[BM][8];
    __shared__ float pdt[BM][8];

    const int t    = threadIdx.x;
    const int lane = t & 63;
    const int wv   = t >> 6;
    const int wrr  = wv >> 1;
    const int wcc  = wv & 1;
    const int quad = lane >> 4;
    const int l15  = lane & 15;
    const int cbx  = blockIdx.x;
    const int row0 = blockIdx.y * BM;

    const bf16_t* bp = Wb + (size_t)(cbx * BN + (t >> 2)) * DD + (t & 3) * 8;
    const int arow = t >> 1;
    const int ah   = t & 1;
    int rowe = row0 + arow; if (rowe >= N) rowe = N - 1;
    const float4* zp4 = (const float4*)(z + (size_t)rowe * DD + ah * 16);

    f32x4 acc[4][4];
    #pragma unroll
    for (int a = 0; a < 4; ++a)
        #pragma unroll
        for (int b = 0; b < 4; ++b) acc[a][b] = (f32x4){0.f, 0.f, 0.f, 0.f};

    float4 v0 = zp4[0], v1 = zp4[1], v2 = zp4[2], v3 = zp4[3];

    for (int kc = 0; kc < DD; kc += BK) {
        if (kc) __syncthreads();
        #pragma unroll
        for (int q = 0; q < 2; ++q) {
            int ldsoff = __builtin_amdgcn_readfirstlane(q * 4096 + wv * 1024);
            __builtin_amdgcn_global_load_lds(
                (const __attribute__((address_space(1))) unsigned int*)(const void*)(bp + (size_t)q * 64 * DD + kc),
                (__attribute__((address_space(3))) unsigned int*)(void*)((char*)Bsl + ldsoff),
                16, 0, 0);
        }
        bf16x8_t lo, hi;
        lo[0]=(bf16_t)v0.x; lo[1]=(bf16_t)v0.y; lo[2]=(bf16_t)v0.z; lo[3]=(bf16_t)v0.w;
        lo[4]=(bf16_t)v1.x; lo[5]=(bf16_t)v1.y; lo[6]=(bf16_t)v1.z; lo[7]=(bf16_t)v1.w;
        hi[0]=(bf16_t)v2.x; hi[1]=(bf16_t)v2.y; hi[2]=(bf16_t)v2.z; hi[3]=(bf16_t)v2.w;
        hi[4]=(bf16_t)v3.x; hi[5]=(bf16_t)v3.y; hi[6]=(bf16_t)v3.z; hi[7]=(bf16_t)v3.w;
        *(bf16x8_t*)(Asl + arow * BK + ah * 16)     = lo;
        *(bf16x8_t*)(Asl + arow * BK + ah * 16 + 8) = hi;
        __syncthreads();
        if (kc + BK < DD) {
            int kf = (kc + BK) >> 2;
            v0 = zp4[kf]; v1 = zp4[kf + 1]; v2 = zp4[kf + 2]; v3 = zp4[kf + 3];
        }
        bf16x8_t af[4];
        #pragma unroll
        for (int rt = 0; rt < 4; ++rt)
            af[rt] = *(const bf16x8_t*)(Asl + (wrr * 64 + rt * 16 + l15) * BK + quad * 8);
        #pragma unroll
        for (int ct = 0; ct < 4; ++ct) {
            bf16x8_t bfv = *(const bf16x8_t*)(Bsl + (wcc * 64 + ct * 16 + l15) * BK + quad * 8);
            #pragma unroll
            for (int rt = 0; rt < 4; ++rt)
                acc[rt][ct] = __builtin_amdgcn_mfma_f32_16x16x32_bf16(af[rt], bfv, acc[rt][ct], 0, 0, 0);
        }
    }

    float bc[4], cc[4];
    #pragma unroll
    for (int ct = 0; ct < 4; ++ct) {
        int col = cbx * BN + wcc * 64 + ct * 16 + l15;
        bc[ct] = bvec[col];
        cc[ct] = cvec[col];
    }
    #pragma unroll
    for (int rt = 0; rt < 4; ++rt) {
        #pragma unroll
        for (int rg = 0; rg < 4; ++rg) {
            float sq = 0.f, dt = 0.f;
            #pragma unroll
            for (int ct = 0; ct < 4; ++ct) {
                float x = acc[rt][ct][rg] + bc[ct];
                sq += x * x;
                dt += x * cc[ct];
            }
            sq += __shfl_xor(sq, 1, 64); dt += __shfl_xor(dt, 1, 64);
            sq += __shfl_xor(sq, 2, 64); dt += __shfl_xor(dt, 2, 64);
            if ((l15 & 3) == 0) {
                int rl = wrr * 64 + rt * 16 + quad * 4 + rg;
                psq[rl][wcc * 4 + (l15 >> 2)] = sq;
                pdt[rl][wcc * 4 + (l15 >> 2)] = dt;
            }
        }
    }
    __syncthreads();
    if (t < BM) {
        int r = row0 + t;
        if (r < N) {
            float sq = 0.f, dt = 0.f;
            #pragma unroll
            for (int i = 0; i < 8; ++i) { sq += psq[t][i]; dt += pdt[t][i]; }
            sqp[(size_t)cbx * npad + r] = sq;
            dtp[(size_t)cbx * npad + r] = dt;
        }
    }
}

// ---------------- combine NCB col-block partials -> dist ----------------
template<int NCB>
__global__ void k_final(const float* __restrict__ sqp, const float* __restrict__ dtp,
                        const float* __restrict__ cninv, float* __restrict__ out,
                        int N, int npad) {
    int r = blockIdx.x * blockDim.x + threadIdx.x;
    if (r < N) {
        float sq = 0.f, dt = 0.f;
        #pragma unroll
        for (int i = 0; i < NCB; ++i) {
            sq += sqp[(size_t)i * npad + r];
            dt += dtp[(size_t)i * npad + r];
        }
        out[r] = 1.0f - dt * cninv[0] / fmaxf(sqrtf(sq), EPSF);
    }
}

extern "C" void kernel_launch(void* const* d_in, const int* in_sizes, int n_in,
                              void* d_out, int out_size, void* d_ws, size_t ws_size,
                              hipStream_t stream)
{
    const float* z = (const float*)d_in[0];
    const float* W = (const float*)d_in[1];
    const float* b = (const float*)d_in[2];
    float* out = (float*)d_out;
    int N = in_sizes[0] / DD;
    int npad = ((N + 255) / 256) * 256;    // 256-aligned for the 256^2 GEMM

    float* ws = (float*)d_ws;
    size_t off = 0;
    float* part   = ws + off; off += (size_t)NPART * DD;
    float* cbar   = ws + off; off += DD;
    float* mpart  = ws + off; off += NPART;
    float* spart  = ws + off; off += NPART;
    float* wscale = ws + off; off += NPART;
    float* cvec   = ws + off; off += DD;
    float* cninv  = ws + off; off += 1;
    off = (off + 3) & ~(size_t)3;
    float* sqp    = ws + off; off += (size_t)4 * npad;
    float* dtp    = ws + off; off += (size_t)4 * npad;
    bf16_t* Wb    = (bf16_t*)(ws + off); off += (size_t)DD * DD / 2;
    bf16_t* zb    = (bf16_t*)(ws + off);
    size_t need_bytes = (off + (size_t)npad * DD / 2) * sizeof(float);
    const bool use_zb = ws_size >= need_bytes;

    int rpb = (N + NPART - 1) / NPART;

    k_convW<<<256, 256, 0, stream>>>(W, Wb);
    if (use_zb) k_colsum<true ><<<NPART, 256, 0, stream>>>(z, zb, part, N, rpb);
    else        k_colsum<false><<<NPART, 256, 0, stream>>>(z, zb, part, N, rpb);
    k_reduceP<<<DD, 256, 0, stream>>>(part, cbar, 1.0f / (float)N);
    k_d2w<<<NPART, 256, 0, stream>>>(z, cbar, part, mpart, spart, N);
    k_combine2<<<1, 256, 0, stream>>>(mpart, spart, wscale);
    k_reducePW<<<DD, 256, 0, stream>>>(part, wscale, cvec);
    k_cnorm<<<1, DD, 0, stream>>>(cvec, cninv);
    if (use_zb) {
        dim3 grid(2, npad / 256);
        k_gemm256<<<grid, 512, 0, stream>>>(zb, Wb, b, cvec, sqp, dtp, N, npad);
        k_final<2><<<(N + 255) / 256, 256, 0, stream>>>(sqp, dtp, cninv, out, N, npad);
    } else {
        dim3 grid(4, npad / BM);
        k_gemm_fb<<<grid, 256, 0, stream>>>(z, Wb, b, cvec, sqp, dtp, N, npad);
        k_final<4><<<(N + 255) / 256, 256, 0, stream>>>(sqp, dtp, cninv, out, N, npad);
    }
}